// Round 1
// baseline (293.727 us; speedup 1.0000x reference)
//
#include <hip/hip_runtime.h>
#include <math.h>

#define Bb 8
#define Tt 256
#define MEL 128
#define Dd 192
#define NCc 20
#define TT 8
#define NTILES (Tt / TT)      // 32
#define ND 4                  // delta ranks (updates at t%64==0)
#define NT 32                 // theta ranks (updates at t%8==0)
#define ETAc 0.9f
#define LRc 0.1f
#define MDEC 0.99f            // 1 - ALPHA
#define EPSc 1e-5f

__device__ __forceinline__ float sigmoidf_(float x) {
    return 1.0f / (1.0f + __expf(-x));
}

// ---------------------------------------------------------------------------
// Kernel: delta memory chain (4 sequential updates at t=0,64,128,192)
// Outputs per batch: K_i, err_i (rank-4 factorization of the 4 M snapshots)
// ---------------------------------------------------------------------------
__global__ __launch_bounds__(256) void delta_chain(
    const float* __restrict__ x, const float* __restrict__ W_in,
    const float* __restrict__ b_in,
    const float* __restrict__ Wk, const float* __restrict__ Wv,
    float* __restrict__ Kd_ws, float* __restrict__ Ed_ws)
{
    int b = blockIdx.x, tid = threadIdx.x;
    __shared__ float XR[ND][MEL];
    __shared__ float XP[ND][Dd];
    __shared__ float K[ND][Dd + 1], E[ND][Dd + 1];
    __shared__ float G[ND * ND];
    __shared__ float mc[ND * ND];

    for (int idx = tid; idx < ND * MEL; idx += 256) {
        int i = idx / MEL, k = idx % MEL;
        XR[i][k] = x[((size_t)b * Tt + 64 * i) * MEL + k];
    }
    __syncthreads();

    if (tid < Dd) {
        float acc[ND] = {0.f, 0.f, 0.f, 0.f};
        for (int k = 0; k < MEL; k++) {
            float w = W_in[k * Dd + tid];
            #pragma unroll
            for (int i = 0; i < ND; i++) acc[i] += XR[i][k] * w;
        }
        float bb = b_in[tid];
        #pragma unroll
        for (int i = 0; i < ND; i++) XP[i][tid] = acc[i] + bb;
    }
    __syncthreads();

    if (tid < Dd) {
        float ak[ND] = {0.f, 0.f, 0.f, 0.f}, av[ND] = {0.f, 0.f, 0.f, 0.f};
        for (int k = 0; k < Dd; k++) {
            float wk = Wk[k * Dd + tid], wv = Wv[k * Dd + tid];
            #pragma unroll
            for (int i = 0; i < ND; i++) { ak[i] += XP[i][k] * wk; av[i] += XP[i][k] * wv; }
        }
        #pragma unroll
        for (int i = 0; i < ND; i++) { K[i][tid] = ak[i]; E[i][tid] = av[i]; }
    }
    __syncthreads();

    // Gram matrix + coefficient table (concurrently, both read-only on K)
    if (tid < ND * ND) {
        int i = tid / ND, j = tid % ND;
        float s = 0.f;
        for (int d = 0; d < Dd; d++) s += K[i][d] * K[j][d];
        G[tid] = s;
    }
    if (tid == 0) {
        for (int q = 0; q < ND * ND; q++) mc[q] = 0.f;
        for (int i = 0; i < ND; i++) {
            float m = 0.f, pw = LRc;
            for (int n = i; n < ND; n++) {
                if (n == i) m = LRc;
                else { pw *= ETAc; m = MDEC * m + pw; }
                mc[n * ND + i] = m;
            }
        }
    }
    __syncthreads();

    // sequential err recurrence: err_i = v_i - sum_{m<i} mc[i-1][m]*(k_i.k_m)*err_m
    for (int i = 1; i < ND; i++) {
        if (tid < Dd) {
            float acc = E[i][tid];
            for (int m = 0; m < i; m++)
                acc -= mc[(i - 1) * ND + m] * G[i * ND + m] * E[m][tid];
            E[i][tid] = acc;
        }
        __syncthreads();
    }

    if (tid < Dd) {
        #pragma unroll
        for (int i = 0; i < ND; i++) {
            Kd_ws[(b * ND + i) * Dd + tid] = K[i][tid];
            Ed_ws[(b * ND + i) * Dd + tid] = E[i][tid];
        }
    }
}

// ---------------------------------------------------------------------------
// Kernel: per-(b,t) pipeline producing x3 (fully parallel, 8-row tiles)
// ---------------------------------------------------------------------------
__global__ __launch_bounds__(256) void pipeline(
    const float* __restrict__ x, const float* __restrict__ W_in, const float* __restrict__ b_in,
    const float* __restrict__ Wv_a, const float* __restrict__ bv_a,
    const float* __restrict__ Wo_a, const float* __restrict__ bo_a,
    const float* __restrict__ ln1_g, const float* __restrict__ ln1_b,
    const float* __restrict__ pw1_w, const float* __restrict__ pw1_b,
    const float* __restrict__ dw_w, const float* __restrict__ dw_b,
    const float* __restrict__ bn_s, const float* __restrict__ bn_b,
    const float* __restrict__ pw2_w, const float* __restrict__ pw2_b,
    const float* __restrict__ Wq_d,
    const float* __restrict__ Kd_ws, const float* __restrict__ Ed_ws,
    float* __restrict__ x3_ws)
{
    int blk = blockIdx.x;
    int b = blk / NTILES, tile = blk % NTILES;
    int t0 = tile * TT;
    int n = t0 / 64;                 // delta memory epoch for this whole tile
    int tid = threadIdx.x;

    __shared__ float XR[TT][MEL];
    __shared__ float XP[TT][Dd];
    __shared__ float KD[ND][Dd + 1], ED[ND][Dd + 1];
    __shared__ float QD[TT][Dd];     // also reused as attn tmp
    __shared__ float X1[TT][Dd];
    __shared__ float X2[TT][Dd];
    __shared__ float LNX[TT][Dd];
    __shared__ float HG[TT][Dd];
    __shared__ float WQ[TT * ND];
    __shared__ float mcd[ND];
    __shared__ float mv[TT][2];

    for (int idx = tid; idx < TT * MEL; idx += 256) {
        int r = idx / MEL, k = idx % MEL;
        XR[r][k] = x[((size_t)b * Tt + t0 + r) * MEL + k];
    }
    for (int idx = tid; idx < ND * Dd; idx += 256) {
        int i = idx / Dd, d2 = idx % Dd;
        KD[i][d2] = Kd_ws[(b * ND + i) * Dd + d2];
        ED[i][d2] = Ed_ws[(b * ND + i) * Dd + d2];
    }
    if (tid < ND) {
        int i = tid; float v = 0.f;
        if (i <= n) {
            float m = LRc, pw = LRc;
            for (int nn = i + 1; nn <= n; nn++) { pw *= ETAc; m = MDEC * m + pw; }
            v = m;
        }
        mcd[i] = v;
    }
    __syncthreads();

    // xp = x @ W_in + b_in
    if (tid < Dd) {
        float acc[TT] = {};
        for (int k = 0; k < MEL; k++) {
            float w = W_in[k * Dd + tid];
            #pragma unroll
            for (int r = 0; r < TT; r++) acc[r] += XR[r][k] * w;
        }
        float bb = b_in[tid];
        #pragma unroll
        for (int r = 0; r < TT; r++) XP[r][tid] = acc[r] + bb;
    }
    __syncthreads();

    // q_d = xp @ Wq_d
    if (tid < Dd) {
        float acc[TT] = {};
        for (int k = 0; k < Dd; k++) {
            float w = Wq_d[k * Dd + tid];
            #pragma unroll
            for (int r = 0; r < TT; r++) acc[r] += XP[r][k] * w;
        }
        #pragma unroll
        for (int r = 0; r < TT; r++) QD[r][tid] = acc[r];
    }
    __syncthreads();

    // q.k_i dots  (32 threads: r in [0,8), i in [0,4))
    if (tid < TT * ND) {
        int r = tid / ND, i = tid % ND;
        float s = 0.f;
        for (int d2 = 0; d2 < Dd; d2++) s += QD[r][d2] * KD[i][d2];
        WQ[tid] = s * mcd[i];
    }
    __syncthreads();

    // x1 = x_t + 0.5 * d_out
    if (tid < Dd) {
        #pragma unroll
        for (int r = 0; r < TT; r++) {
            float dout = 0.f;
            #pragma unroll
            for (int i = 0; i < ND; i++) dout += WQ[r * ND + i] * ED[i][tid];
            X1[r][tid] = XP[r][tid] + 0.5f * dout;
        }
    }
    __syncthreads();

    // attn V proj
    if (tid < Dd) {
        float acc[TT] = {};
        for (int k = 0; k < Dd; k++) {
            float w = Wv_a[k * Dd + tid];
            #pragma unroll
            for (int r = 0; r < TT; r++) acc[r] += X1[r][k] * w;
        }
        float bb = bv_a[tid];
        #pragma unroll
        for (int r = 0; r < TT; r++) QD[r][tid] = acc[r] + bb;
    }
    __syncthreads();

    // attn out proj + residual -> x2
    if (tid < Dd) {
        float acc[TT] = {};
        for (int k = 0; k < Dd; k++) {
            float w = Wo_a[k * Dd + tid];
            #pragma unroll
            for (int r = 0; r < TT; r++) acc[r] += QD[r][k] * w;
        }
        float bb = bo_a[tid];
        #pragma unroll
        for (int r = 0; r < TT; r++) X2[r][tid] = X1[r][tid] + acc[r] + bb;
    }
    __syncthreads();

    // LN1 stats: 8 groups of 32 lanes
    {
        int r = tid >> 5, j = tid & 31;
        float s = 0.f, sq = 0.f;
        for (int d2 = j; d2 < Dd; d2 += 32) { float v = X2[r][d2]; s += v; sq += v * v; }
        for (int off = 16; off > 0; off >>= 1) {
            s += __shfl_down(s, off, 32); sq += __shfl_down(sq, off, 32);
        }
        if (j == 0) {
            float mean = s / Dd;
            mv[r][0] = mean;
            mv[r][1] = rsqrtf(sq / Dd - mean * mean + EPSc);
        }
    }
    __syncthreads();
    if (tid < Dd) {
        float g = ln1_g[tid], bb = ln1_b[tid];
        #pragma unroll
        for (int r = 0; r < TT; r++)
            LNX[r][tid] = (X2[r][tid] - mv[r][0]) * mv[r][1] * g + bb;
    }
    __syncthreads();

    // pw1 (both GLU halves per thread) + GLU + dw + bn + silu
    if (tid < Dd) {
        float aa[TT] = {}, gg[TT] = {};
        for (int k = 0; k < Dd; k++) {
            float wa = pw1_w[k * 2 * Dd + tid], wg = pw1_w[k * 2 * Dd + tid + Dd];
            #pragma unroll
            for (int r = 0; r < TT; r++) { float l = LNX[r][k]; aa[r] += l * wa; gg[r] += l * wg; }
        }
        float ba = pw1_b[tid], bg = pw1_b[tid + Dd];
        float dww = dw_w[tid], dwb = dw_b[tid], bns = bn_s[tid], bnb = bn_b[tid];
        #pragma unroll
        for (int r = 0; r < TT; r++) {
            float a = aa[r] + ba, g = gg[r] + bg;
            float h = a * sigmoidf_(g);
            h = h * dww + dwb;
            h = h * bns + bnb;
            h = h * sigmoidf_(h);
            HG[r][tid] = h;
        }
    }
    __syncthreads();

    // pw2 + residual -> x3, store
    if (tid < Dd) {
        float acc[TT] = {};
        for (int k = 0; k < Dd; k++) {
            float w = pw2_w[k * Dd + tid];
            #pragma unroll
            for (int r = 0; r < TT; r++) acc[r] += HG[r][k] * w;
        }
        float bb = pw2_b[tid];
        #pragma unroll
        for (int r = 0; r < TT; r++) {
            float x3v = X2[r][tid] + acc[r] + bb;
            x3_ws[((size_t)b * Tt + t0 + r) * Dd + tid] = x3v;
        }
    }
}

// ---------------------------------------------------------------------------
// Kernel: theta memory chain (32 sequential rank-1 updates at t=0,8,...,248)
// ---------------------------------------------------------------------------
__global__ __launch_bounds__(256) void theta_chain(
    const float* __restrict__ x3_ws,
    const float* __restrict__ Wk, const float* __restrict__ Wv,
    float* __restrict__ Kt_ws, float* __restrict__ Et_ws)
{
    int b = blockIdx.x, tid = threadIdx.x;
    __shared__ float XR[TT][Dd];
    __shared__ float K[NT][Dd + 1], E[NT][Dd + 1];
    __shared__ float G[NT * NT];
    __shared__ float mc[NT * NT];

    // K,V projections of the 32 update rows, in 4 chunks of 8 rows
    for (int c = 0; c < 4; c++) {
        for (int idx = tid; idx < TT * Dd; idx += 256) {
            int r = idx / Dd, d2 = idx % Dd;
            int i = c * TT + r;
            XR[r][d2] = x3_ws[((size_t)b * Tt + 8 * i) * Dd + d2];
        }
        __syncthreads();
        if (tid < Dd) {
            float ak[TT] = {}, av[TT] = {};
            for (int k = 0; k < Dd; k++) {
                float wk = Wk[k * Dd + tid], wv = Wv[k * Dd + tid];
                #pragma unroll
                for (int r = 0; r < TT; r++) { float xv = XR[r][k]; ak[r] += xv * wk; av[r] += xv * wv; }
            }
            #pragma unroll
            for (int r = 0; r < TT; r++) { K[c * TT + r][tid] = ak[r]; E[c * TT + r][tid] = av[r]; }
        }
        __syncthreads();
    }

    // coefficient table mc[n][i] (thread i owns column i; recurrence over n)
    if (tid < NT) {
        int i = tid;
        float m = 0.f, pw = LRc;
        for (int nn = 0; nn < NT; nn++) {
            float v;
            if (nn < i) v = 0.f;
            else if (nn == i) { m = LRc; v = m; }
            else { pw *= ETAc; m = MDEC * m + pw; v = m; }
            mc[nn * NT + i] = v;
        }
    }
    // Gram matrix: 1024 dots, 4 per thread
    for (int p = tid; p < NT * NT; p += 256) {
        int i = p >> 5, j = p & 31;
        float s = 0.f;
        for (int d2 = 0; d2 < Dd; d2++) s += K[i][d2] * K[j][d2];
        G[p] = s;
    }
    __syncthreads();

    // sequential err recurrence
    for (int i = 1; i < NT; i++) {
        if (tid < Dd) {
            float acc = E[i][tid];
            for (int m = 0; m < i; m++)
                acc -= mc[(i - 1) * NT + m] * G[i * NT + m] * E[m][tid];
            E[i][tid] = acc;
        }
        __syncthreads();
    }

    if (tid < Dd) {
        for (int i = 0; i < NT; i++) {
            Kt_ws[(b * NT + i) * Dd + tid] = K[i][tid];
            Et_ws[(b * NT + i) * Dd + tid] = E[i][tid];
        }
    }
}

// ---------------------------------------------------------------------------
// Kernel: theta retrieval + x4 + LN2 + pooled accumulation
// ---------------------------------------------------------------------------
__global__ __launch_bounds__(256) void retrieve(
    const float* __restrict__ x3_ws, const float* __restrict__ Wq,
    const float* __restrict__ Kt_ws, const float* __restrict__ Et_ws,
    const float* __restrict__ ln2_g, const float* __restrict__ ln2_b,
    float* __restrict__ pooled)
{
    int blk = blockIdx.x;
    int b = blk / NTILES, tile = blk % NTILES;
    int t0 = tile * TT;
    int n = tile;                      // t0/8: theta epoch, constant per tile
    int tid = threadIdx.x;

    __shared__ float KT[NT][Dd + 1], ET[NT][Dd + 1];
    __shared__ float XS[TT][Dd];
    __shared__ float Q[TT][Dd];
    __shared__ float WQ[TT * NT];
    __shared__ float mcr[NT];
    __shared__ float mv[TT][2];

    for (int idx = tid; idx < NT * Dd; idx += 256) {
        int i = idx / Dd, d2 = idx % Dd;
        KT[i][d2] = Kt_ws[(b * NT + i) * Dd + d2];
        ET[i][d2] = Et_ws[(b * NT + i) * Dd + d2];
    }
    for (int idx = tid; idx < TT * Dd; idx += 256) {
        int r = idx / Dd, d2 = idx % Dd;
        XS[r][d2] = x3_ws[((size_t)b * Tt + t0 + r) * Dd + d2];
    }
    if (tid < NT) {
        int i = tid; float v = 0.f;
        if (i <= n) {
            float m = LRc, pw = LRc;
            for (int nn = i + 1; nn <= n; nn++) { pw *= ETAc; m = MDEC * m + pw; }
            v = m;
        }
        mcr[i] = v;
    }
    __syncthreads();

    // q = x3 @ Wq_t
    if (tid < Dd) {
        float acc[TT] = {};
        for (int k = 0; k < Dd; k++) {
            float w = Wq[k * Dd + tid];
            #pragma unroll
            for (int r = 0; r < TT; r++) acc[r] += XS[r][k] * w;
        }
        #pragma unroll
        for (int r = 0; r < TT; r++) Q[r][tid] = acc[r];
    }
    __syncthreads();

    // q.k_i dots: tid = r*32 + i (KT padded stride 193 -> conflict-free)
    {
        int r = tid >> 5, i = tid & 31;
        float s = 0.f;
        for (int d2 = 0; d2 < Dd; d2++) s += Q[r][d2] * KT[i][d2];
        WQ[tid] = s * mcr[i];
    }
    __syncthreads();

    // t_out, x4 (in place over XS)
    if (tid < Dd) {
        float acc[TT] = {};
        for (int i = 0; i < NT; i++) {
            float e = ET[i][tid];
            #pragma unroll
            for (int r = 0; r < TT; r++) acc[r] += WQ[r * NT + i] * e;
        }
        #pragma unroll
        for (int r = 0; r < TT; r++) XS[r][tid] = XS[r][tid] + 0.5f * acc[r];
    }
    __syncthreads();

    // LN2 stats
    {
        int r = tid >> 5, j = tid & 31;
        float s = 0.f, sq = 0.f;
        for (int d2 = j; d2 < Dd; d2 += 32) { float v = XS[r][d2]; s += v; sq += v * v; }
        for (int off = 16; off > 0; off >>= 1) {
            s += __shfl_down(s, off, 32); sq += __shfl_down(sq, off, 32);
        }
        if (j == 0) {
            float mean = s / Dd;
            mv[r][0] = mean;
            mv[r][1] = rsqrtf(sq / Dd - mean * mean + EPSc);
        }
    }
    __syncthreads();

    if (tid < Dd) {
        float g = ln2_g[tid], bb = ln2_b[tid];
        float sum = 0.f;
        #pragma unroll
        for (int r = 0; r < TT; r++)
            sum += (XS[r][tid] - mv[r][0]) * mv[r][1] * g + bb;
        atomicAdd(&pooled[b * Dd + tid], sum);
    }
}

// ---------------------------------------------------------------------------
// Kernel: classifier head  out = (pooled/T) @ Wc + bc
// ---------------------------------------------------------------------------
__global__ __launch_bounds__(256) void head(
    const float* __restrict__ pooled, const float* __restrict__ Wc,
    const float* __restrict__ bc, float* __restrict__ out)
{
    int tid = threadIdx.x;
    if (tid < Bb * NCc) {
        int b = tid / NCc, c = tid % NCc;
        float s = 0.f;
        for (int d2 = 0; d2 < Dd; d2++) s += pooled[b * Dd + d2] * Wc[d2 * NCc + c];
        out[tid] = s * (1.0f / Tt) + bc[c];
    }
}

extern "C" void kernel_launch(void* const* d_in, const int* in_sizes, int n_in,
                              void* d_out, int out_size, void* d_ws, size_t ws_size,
                              hipStream_t stream) {
    const float* x     = (const float*)d_in[0];
    const float* W_in  = (const float*)d_in[1];
    const float* b_in  = (const float*)d_in[2];
    const float* Wv_a  = (const float*)d_in[3];
    const float* bv_a  = (const float*)d_in[4];
    const float* Wo_a  = (const float*)d_in[5];
    const float* bo_a  = (const float*)d_in[6];
    const float* ln1_g = (const float*)d_in[7];
    const float* ln1_b = (const float*)d_in[8];
    const float* pw1_w = (const float*)d_in[9];
    const float* pw1_b = (const float*)d_in[10];
    const float* dw_w  = (const float*)d_in[11];
    const float* dw_b  = (const float*)d_in[12];
    const float* bn_s  = (const float*)d_in[13];
    const float* bn_b  = (const float*)d_in[14];
    const float* pw2_w = (const float*)d_in[15];
    const float* pw2_b = (const float*)d_in[16];
    const float* Wk_t  = (const float*)d_in[17];
    const float* Wv_t  = (const float*)d_in[18];
    const float* Wq_t  = (const float*)d_in[19];
    const float* Wk_d  = (const float*)d_in[20];
    const float* Wv_d  = (const float*)d_in[21];
    const float* Wq_d  = (const float*)d_in[22];
    const float* ln2_g = (const float*)d_in[23];
    const float* ln2_b = (const float*)d_in[24];
    const float* Wc    = (const float*)d_in[25];
    const float* bc    = (const float*)d_in[26];

    float* ws     = (float*)d_ws;
    float* x3_ws  = ws;                               // B*T*D
    float* Kd_ws  = x3_ws + (size_t)Bb * Tt * Dd;     // B*ND*D
    float* Ed_ws  = Kd_ws + Bb * ND * Dd;             // B*ND*D
    float* Kt_ws  = Ed_ws + Bb * ND * Dd;             // B*NT*D
    float* Et_ws  = Kt_ws + Bb * NT * Dd;             // B*NT*D
    float* pooled = Et_ws + Bb * NT * Dd;             // B*D

    hipMemsetAsync(pooled, 0, Bb * Dd * sizeof(float), stream);

    delta_chain<<<Bb, 256, 0, stream>>>(x, W_in, b_in, Wk_d, Wv_d, Kd_ws, Ed_ws);
    pipeline<<<Bb * NTILES, 256, 0, stream>>>(
        x, W_in, b_in, Wv_a, bv_a, Wo_a, bo_a, ln1_g, ln1_b,
        pw1_w, pw1_b, dw_w, dw_b, bn_s, bn_b, pw2_w, pw2_b,
        Wq_d, Kd_ws, Ed_ws, x3_ws);
    theta_chain<<<Bb, 256, 0, stream>>>(x3_ws, Wk_t, Wv_t, Kt_ws, Et_ws);
    retrieve<<<Bb * NTILES, 256, 0, stream>>>(
        x3_ws, Wq_t, Kt_ws, Et_ws, ln2_g, ln2_b, pooled);
    head<<<1, 256, 0, stream>>>(pooled, Wc, bc, (float*)d_out);
}

// Round 2
// 254.454 us; speedup vs baseline: 1.1543x; 1.1543x over previous
//
#include <hip/hip_runtime.h>
#include <math.h>

#define Bb 8
#define Tt 256
#define MEL 128
#define Dd 192
#define NCc 20
#define ND 4                  // delta ranks (updates at t%64==0)
#define NT 32                 // theta ranks (updates at t%8==0)
#define ETAc 0.9f
#define LRc 0.1f
#define MDEC 0.99f            // 1 - ALPHA
#define EPSc 1e-5f
#define PTT 4                 // pipeline rows per block
#define PTILES (Tt / PTT)     // 64
#define RTT 8                 // retrieve rows per block
#define RTILES (Tt / RTT)     // 32
#define KPAD 196              // padded LDS row (196%4==0 -> float4-aligned rows)

__device__ __forceinline__ float sigmoidf_(float x) {
    return 1.0f / (1.0f + __expf(-x));
}

// ---------------------------------------------------------------------------
// prep: transpose all weight matrices into workspace so each compute thread
// can stream its own contiguous row with float4 loads.
// Grid: 128 (W_in rows) + 10*192 rows = 2048 blocks.
// ---------------------------------------------------------------------------
__global__ __launch_bounds__(256) void prep(
    const float* __restrict__ W_in, const float* __restrict__ Wq_d,
    const float* __restrict__ pw1_w, const float* __restrict__ pw2_w,
    const float* __restrict__ Wq_t, const float* __restrict__ Wk_d,
    const float* __restrict__ Wv_d, const float* __restrict__ Wk_t,
    const float* __restrict__ Wv_t, const float* __restrict__ Wv_a,
    const float* __restrict__ Wo_a,
    float* __restrict__ WinT, float* __restrict__ WqdT,
    float* __restrict__ pw1aT, float* __restrict__ pw1gT,
    float* __restrict__ pw2T, float* __restrict__ WqtT,
    float* __restrict__ WkdT, float* __restrict__ WvdT,
    float* __restrict__ WktT, float* __restrict__ WvtT,
    float* __restrict__ WvaT, float* __restrict__ WoaT)
{
    int blk = blockIdx.x, tid = threadIdx.x;
    if (blk < 128) {                       // W_in: [128][192] -> WinT [192][128]
        if (tid < Dd) WinT[tid * MEL + blk] = W_in[blk * Dd + tid];
        return;
    }
    int q = blk - 128;
    int mat = q / Dd, k = q - mat * Dd;
    if (mat == 1) {                        // pw1: [192][384] -> two [192][192]
        for (int j = tid; j < 2 * Dd; j += 256) {
            float v = pw1_w[k * 2 * Dd + j];
            if (j < Dd) pw1aT[j * Dd + k] = v;
            else        pw1gT[(j - Dd) * Dd + k] = v;
        }
        return;
    }
    if (tid >= Dd) return;
    const float* src; float* dst;
    switch (mat) {
        case 0: src = Wq_d;  dst = WqdT; break;
        case 2: src = pw2_w; dst = pw2T; break;
        case 3: src = Wq_t;  dst = WqtT; break;
        case 4: src = Wk_d;  dst = WkdT; break;
        case 5: src = Wv_d;  dst = WvdT; break;
        case 6: src = Wk_t;  dst = WktT; break;
        case 7: src = Wv_t;  dst = WvtT; break;
        case 8: src = Wv_a;  dst = WvaT; break;
        default: src = Wo_a; dst = WoaT; break;
    }
    dst[tid * Dd + k] = src[k * Dd + tid];
}

// ---------------------------------------------------------------------------
// delta_proj: grid B*ND = 32 blocks. One update row each: xp -> k, v.
// ---------------------------------------------------------------------------
__global__ __launch_bounds__(256) void delta_proj(
    const float* __restrict__ x, const float* __restrict__ b_in,
    const float* __restrict__ WinT, const float* __restrict__ WkdT,
    const float* __restrict__ WvdT,
    float* __restrict__ Kd_ws, float* __restrict__ Ed_ws)
{
    int b = blockIdx.x >> 2, i = blockIdx.x & 3, tid = threadIdx.x;
    __shared__ __align__(16) float XR[MEL];
    __shared__ __align__(16) float XP[Dd];
    if (tid < MEL / 4)
        ((float4*)XR)[tid] = ((const float4*)&x[((size_t)b * Tt + 64 * i) * MEL])[tid];
    __syncthreads();
    if (tid < Dd) {
        const float4* w = (const float4*)&WinT[tid * MEL];
        float acc = b_in[tid];
        #pragma unroll 4
        for (int kk = 0; kk < MEL / 4; kk++) {
            float4 wv = w[kk];
            float4 xv = ((const float4*)XR)[kk];
            acc += wv.x * xv.x + wv.y * xv.y + wv.z * xv.z + wv.w * xv.w;
        }
        XP[tid] = acc;
    }
    __syncthreads();
    if (tid < Dd) {
        const float4* wk = (const float4*)&WkdT[tid * Dd];
        const float4* wv = (const float4*)&WvdT[tid * Dd];
        float ak = 0.f, av = 0.f;
        #pragma unroll 4
        for (int kk = 0; kk < Dd / 4; kk++) {
            float4 a = wk[kk], c = wv[kk];
            float4 xv = ((const float4*)XP)[kk];
            ak += a.x * xv.x + a.y * xv.y + a.z * xv.z + a.w * xv.w;
            av += c.x * xv.x + c.y * xv.y + c.z * xv.z + c.w * xv.w;
        }
        Kd_ws[(b * ND + i) * Dd + tid] = ak;
        Ed_ws[(b * ND + i) * Dd + tid] = av;
    }
}

// ---------------------------------------------------------------------------
// delta_solve: grid B. Gram 4x4 + 3-step recurrence; rewrites Ed_ws.
// ---------------------------------------------------------------------------
__global__ __launch_bounds__(256) void delta_solve(
    const float* __restrict__ Kd_ws, float* __restrict__ Ed_ws)
{
    int b = blockIdx.x, tid = threadIdx.x;
    __shared__ float K[ND][Dd], E[ND][Dd];
    __shared__ float G[ND * ND], mc[ND * ND];
    for (int idx = tid; idx < ND * Dd; idx += 256) {
        int i = idx / Dd, d = idx - i * Dd;
        K[i][d] = Kd_ws[(b * ND + i) * Dd + d];
        E[i][d] = Ed_ws[(b * ND + i) * Dd + d];
    }
    __syncthreads();
    if (tid < ND * ND) {
        int i = tid >> 2, j = tid & 3;
        float s = 0.f;
        for (int d = 0; d < Dd; d++) s += K[i][d] * K[j][d];
        G[tid] = s;
    }
    if (tid == 32) {
        for (int q = 0; q < ND * ND; q++) mc[q] = 0.f;
        for (int i = 0; i < ND; i++) {
            float m = 0.f, pw = LRc;
            for (int n = i; n < ND; n++) {
                if (n == i) m = LRc;
                else { pw *= ETAc; m = MDEC * m + pw; }
                mc[n * ND + i] = m;
            }
        }
    }
    __syncthreads();
    for (int i = 1; i < ND; i++) {
        if (tid < Dd) {
            float acc = E[i][tid];
            for (int m = 0; m < i; m++)
                acc -= mc[(i - 1) * ND + m] * G[i * ND + m] * E[m][tid];
            E[i][tid] = acc;
        }
        __syncthreads();
    }
    if (tid < Dd)
        for (int i = 0; i < ND; i++) Ed_ws[(b * ND + i) * Dd + tid] = E[i][tid];
}

// acc[r] += sum_k WT[tid][k] * SRC[r][k]   (float4 weight stream, LDS broadcast x)
template<int KLEN, int SSTRIDE>
__device__ __forceinline__ void mm4(const float* __restrict__ wrow,
                                    const float* __restrict__ src,
                                    float acc[PTT])
{
    const float4* w4 = (const float4*)wrow;
    #pragma unroll 4
    for (int kk = 0; kk < KLEN / 4; kk++) {
        float4 w = w4[kk];
        #pragma unroll
        for (int r = 0; r < PTT; r++) {
            float4 xv = *(const float4*)(src + r * SSTRIDE + kk * 4);
            acc[r] += w.x * xv.x + w.y * xv.y + w.z * xv.z + w.w * xv.w;
        }
    }
}

// ---------------------------------------------------------------------------
// pipeline: grid B*64 (4 rows/block). Produces x3, q_t, and (even tiles)
// theta k/v for the t%8==0 update row.
// ---------------------------------------------------------------------------
__global__ __launch_bounds__(256) void pipeline(
    const float* __restrict__ x, const float* __restrict__ b_in,
    const float* __restrict__ bv_a, const float* __restrict__ bo_a,
    const float* __restrict__ ln1_g, const float* __restrict__ ln1_b,
    const float* __restrict__ pw1_b, const float* __restrict__ dw_w,
    const float* __restrict__ dw_b, const float* __restrict__ bn_s,
    const float* __restrict__ bn_b, const float* __restrict__ pw2_b,
    const float* __restrict__ WinT, const float* __restrict__ WqdT,
    const float* __restrict__ WvaT, const float* __restrict__ WoaT,
    const float* __restrict__ pw1aT, const float* __restrict__ pw1gT,
    const float* __restrict__ pw2T, const float* __restrict__ WqtT,
    const float* __restrict__ WktT, const float* __restrict__ WvtT,
    const float* __restrict__ Kd_ws, const float* __restrict__ Ed_ws,
    float* __restrict__ x3_ws, float* __restrict__ q_ws,
    float* __restrict__ Kt_ws, float* __restrict__ Et_ws)
{
    int blk = blockIdx.x;
    int b = blk >> 6, tile = blk & 63;
    int t0 = tile * PTT, n = tile >> 4;   // delta epoch = floor(t/64), tile-uniform
    int tid = threadIdx.x;

    __shared__ __align__(16) float XR[PTT][MEL];
    __shared__ __align__(16) float XP[PTT][Dd];
    __shared__ __align__(16) float KD[ND][Dd], ED[ND][Dd];
    __shared__ __align__(16) float TA[PTT][Dd];
    __shared__ __align__(16) float X1[PTT][Dd];
    __shared__ __align__(16) float X2[PTT][Dd];
    __shared__ __align__(16) float LNX[PTT][Dd];
    __shared__ __align__(16) float HG[PTT][Dd];
    __shared__ __align__(16) float X3[PTT][Dd];
    __shared__ float WQs[PTT * ND];
    __shared__ float mcd[ND];
    __shared__ float mv[PTT][2];

    if (tid < 128) {
        int r = tid >> 5, c = tid & 31;
        ((float4*)XR[r])[c] = ((const float4*)&x[((size_t)b * Tt + t0 + r) * MEL])[c];
    }
    if (tid < 192) {
        int i = tid / 48, c = tid - i * 48;
        ((float4*)KD[i])[c] = ((const float4*)&Kd_ws[(b * ND + i) * Dd])[c];
        ((float4*)ED[i])[c] = ((const float4*)&Ed_ws[(b * ND + i) * Dd])[c];
    }
    if (tid >= 252) {
        int i = tid - 252; float v = 0.f;
        if (i <= n) {
            float m = LRc, pw = LRc;
            for (int nn = i + 1; nn <= n; nn++) { pw *= ETAc; m = MDEC * m + pw; }
            v = m;
        }
        mcd[i] = v;
    }
    __syncthreads();

    // xp = x @ W_in + b_in
    if (tid < Dd) {
        float acc[PTT]; float bb = b_in[tid];
        #pragma unroll
        for (int r = 0; r < PTT; r++) acc[r] = bb;
        mm4<MEL, MEL>(&WinT[tid * MEL], &XR[0][0], acc);
        #pragma unroll
        for (int r = 0; r < PTT; r++) XP[r][tid] = acc[r];
    }
    __syncthreads();

    // q_d = xp @ Wq_d
    if (tid < Dd) {
        float acc[PTT] = {};
        mm4<Dd, Dd>(&WqdT[tid * Dd], &XP[0][0], acc);
        #pragma unroll
        for (int r = 0; r < PTT; r++) TA[r][tid] = acc[r];
    }
    __syncthreads();

    // q.k_i dots
    if (tid < PTT * ND) {
        int r = tid >> 2, i = tid & 3;
        float s = 0.f;
        for (int d = 0; d < Dd; d++) s += TA[r][d] * KD[i][d];
        WQs[tid] = s * mcd[i];
    }
    __syncthreads();

    // x1 = xp + 0.5 * d_out
    if (tid < Dd) {
        #pragma unroll
        for (int r = 0; r < PTT; r++) {
            float dout = 0.f;
            #pragma unroll
            for (int i = 0; i < ND; i++) dout += WQs[r * ND + i] * ED[i][tid];
            X1[r][tid] = XP[r][tid] + 0.5f * dout;
        }
    }
    __syncthreads();

    // attn V proj
    if (tid < Dd) {
        float acc[PTT]; float bb = bv_a[tid];
        #pragma unroll
        for (int r = 0; r < PTT; r++) acc[r] = bb;
        mm4<Dd, Dd>(&WvaT[tid * Dd], &X1[0][0], acc);
        #pragma unroll
        for (int r = 0; r < PTT; r++) TA[r][tid] = acc[r];
    }
    __syncthreads();

    // attn out proj + residual -> x2
    if (tid < Dd) {
        float acc[PTT]; float bb = bo_a[tid];
        #pragma unroll
        for (int r = 0; r < PTT; r++) acc[r] = bb;
        mm4<Dd, Dd>(&WoaT[tid * Dd], &TA[0][0], acc);
        #pragma unroll
        for (int r = 0; r < PTT; r++) X2[r][tid] = X1[r][tid] + acc[r];
    }
    __syncthreads();

    // LN1 stats (4 groups of 32 lanes)
    if (tid < 128) {
        int r = tid >> 5, j = tid & 31;
        float s = 0.f, sq = 0.f;
        for (int d = j; d < Dd; d += 32) { float v = X2[r][d]; s += v; sq += v * v; }
        for (int off = 16; off > 0; off >>= 1) {
            s += __shfl_down(s, off, 32); sq += __shfl_down(sq, off, 32);
        }
        if (j == 0) {
            float mean = s / Dd;
            mv[r][0] = mean;
            mv[r][1] = rsqrtf(sq / Dd - mean * mean + EPSc);
        }
    }
    __syncthreads();
    if (tid < Dd) {
        float g = ln1_g[tid], bb = ln1_b[tid];
        #pragma unroll
        for (int r = 0; r < PTT; r++)
            LNX[r][tid] = (X2[r][tid] - mv[r][0]) * mv[r][1] * g + bb;
    }
    __syncthreads();

    // pw1 (dual weight stream) + GLU + dw + bn + silu
    if (tid < Dd) {
        float aa[PTT], gg[PTT];
        float ba = pw1_b[tid], bg = pw1_b[tid + Dd];
        #pragma unroll
        for (int r = 0; r < PTT; r++) { aa[r] = ba; gg[r] = bg; }
        const float4* wa4 = (const float4*)&pw1aT[tid * Dd];
        const float4* wg4 = (const float4*)&pw1gT[tid * Dd];
        #pragma unroll 4
        for (int kk = 0; kk < Dd / 4; kk++) {
            float4 wa = wa4[kk], wg = wg4[kk];
            #pragma unroll
            for (int r = 0; r < PTT; r++) {
                float4 xv = *(const float4*)&LNX[r][kk * 4];
                aa[r] += wa.x * xv.x + wa.y * xv.y + wa.z * xv.z + wa.w * xv.w;
                gg[r] += wg.x * xv.x + wg.y * xv.y + wg.z * xv.z + wg.w * xv.w;
            }
        }
        float dww = dw_w[tid], dwb = dw_b[tid], bns = bn_s[tid], bnb = bn_b[tid];
        #pragma unroll
        for (int r = 0; r < PTT; r++) {
            float h = aa[r] * sigmoidf_(gg[r]);
            h = h * dww + dwb;
            h = h * bns + bnb;
            h = h * sigmoidf_(h);
            HG[r][tid] = h;
        }
    }
    __syncthreads();

    // pw2 + residual -> x3
    if (tid < Dd) {
        float acc[PTT]; float bb = pw2_b[tid];
        #pragma unroll
        for (int r = 0; r < PTT; r++) acc[r] = bb;
        mm4<Dd, Dd>(&pw2T[tid * Dd], &HG[0][0], acc);
        #pragma unroll
        for (int r = 0; r < PTT; r++) {
            float v = X2[r][tid] + acc[r];
            X3[r][tid] = v;
            x3_ws[((size_t)b * Tt + t0 + r) * Dd + tid] = v;
        }
    }
    __syncthreads();

    // q_t = x3 @ Wq_t  (theta retrieval query, consumed by `retrieve`)
    if (tid < Dd) {
        float acc[PTT] = {};
        mm4<Dd, Dd>(&WqtT[tid * Dd], &X3[0][0], acc);
        #pragma unroll
        for (int r = 0; r < PTT; r++)
            q_ws[((size_t)b * Tt + t0 + r) * Dd + tid] = acc[r];
    }

    // theta k/v for the update row (t0 % 8 == 0 <=> even tile, row 0)
    if ((tile & 1) == 0 && tid < Dd) {
        int i8 = tile >> 1;
        const float4* wk = (const float4*)&WktT[tid * Dd];
        const float4* wv = (const float4*)&WvtT[tid * Dd];
        float ak = 0.f, av = 0.f;
        #pragma unroll 4
        for (int kk = 0; kk < Dd / 4; kk++) {
            float4 a = wk[kk], c = wv[kk];
            float4 xv = *(const float4*)&X3[0][kk * 4];
            ak += a.x * xv.x + a.y * xv.y + a.z * xv.z + a.w * xv.w;
            av += c.x * xv.x + c.y * xv.y + c.z * xv.z + c.w * xv.w;
        }
        Kt_ws[(b * NT + i8) * Dd + tid] = ak;
        Et_ws[(b * NT + i8) * Dd + tid] = av;
    }
}

// ---------------------------------------------------------------------------
// theta_solve: grid B. Gram 32x32 + 31-step recurrence; rewrites Et_ws.
// ---------------------------------------------------------------------------
__global__ __launch_bounds__(256) void theta_solve(
    const float* __restrict__ Kt_ws, float* __restrict__ Et_ws)
{
    int b = blockIdx.x, tid = threadIdx.x;
    __shared__ __align__(16) float K[NT][KPAD], E[NT][KPAD];
    __shared__ float G[NT * NT], mc[NT * NT];

    for (int idx = tid; idx < NT * 48; idx += 256) {
        int i = idx / 48, c = idx - i * 48;
        ((float4*)K[i])[c] = ((const float4*)&Kt_ws[(b * NT + i) * Dd])[c];
        ((float4*)E[i])[c] = ((const float4*)&Et_ws[(b * NT + i) * Dd])[c];
    }
    if (tid < NT) {
        int i = tid;
        float m = 0.f, pw = LRc;
        for (int nn = 0; nn < NT; nn++) {
            float v;
            if (nn < i) v = 0.f;
            else if (nn == i) { m = LRc; v = m; }
            else { pw *= ETAc; m = MDEC * m + pw; v = m; }
            mc[nn * NT + i] = v;
        }
    }
    __syncthreads();
    for (int p = tid; p < NT * NT; p += 256) {
        int i = p >> 5, j = p & 31;
        const float4* ki = (const float4*)K[i];
        const float4* kj = (const float4*)K[j];
        float s = 0.f;
        #pragma unroll 4
        for (int kk = 0; kk < 48; kk++) {
            float4 a = ki[kk], c = kj[kk];
            s += a.x * c.x + a.y * c.y + a.z * c.z + a.w * c.w;
        }
        G[p] = s;
    }
    __syncthreads();
    for (int i = 1; i < NT; i++) {
        if (tid < Dd) {
            float acc = E[i][tid];
            for (int m = 0; m < i; m++)
                acc -= mc[(i - 1) * NT + m] * G[i * NT + m] * E[m][tid];
            E[i][tid] = acc;
        }
        __syncthreads();
    }
    if (tid < Dd)
        for (int i = 0; i < NT; i++) Et_ws[(b * NT + i) * Dd + tid] = E[i][tid];
}

// ---------------------------------------------------------------------------
// retrieve: grid B*32 (8 rows/block). No weight streams: dots + rank-32
// combine + LN2 + pooled accumulation.
// ---------------------------------------------------------------------------
__global__ __launch_bounds__(256) void retrieve(
    const float* __restrict__ x3_ws, const float* __restrict__ q_ws,
    const float* __restrict__ Kt_ws, const float* __restrict__ Et_ws,
    const float* __restrict__ ln2_g, const float* __restrict__ ln2_b,
    float* __restrict__ pooled)
{
    int blk = blockIdx.x, b = blk >> 5, tile = blk & 31;
    int t0 = tile * RTT, n = tile;       // theta epoch = floor(t/8), tile-uniform
    int tid = threadIdx.x;

    __shared__ __align__(16) float KT[NT][KPAD], ET[NT][KPAD];
    __shared__ __align__(16) float XS[RTT][Dd], Q[RTT][Dd];
    __shared__ float WQ[RTT * NT];
    __shared__ float mcr[NT];
    __shared__ float mv[RTT][2];

    for (int idx = tid; idx < NT * 48; idx += 256) {
        int i = idx / 48, c = idx - i * 48;
        ((float4*)KT[i])[c] = ((const float4*)&Kt_ws[(b * NT + i) * Dd])[c];
        ((float4*)ET[i])[c] = ((const float4*)&Et_ws[(b * NT + i) * Dd])[c];
    }
    for (int idx = tid; idx < RTT * 48; idx += 256) {
        int r = idx / 48, c = idx - r * 48;
        ((float4*)XS[r])[c] = ((const float4*)&x3_ws[((size_t)b * Tt + t0 + r) * Dd])[c];
        ((float4*)Q[r])[c]  = ((const float4*)&q_ws[((size_t)b * Tt + t0 + r) * Dd])[c];
    }
    if (tid < NT) {
        int i = tid; float v = 0.f;
        if (i <= n) {
            float m = LRc, pw = LRc;
            for (int nn = i + 1; nn <= n; nn++) { pw *= ETAc; m = MDEC * m + pw; }
            v = m;
        }
        mcr[i] = v;
    }
    __syncthreads();

    // q.k_i dots: tid = r*32 + i
    {
        int r = tid >> 5, i = tid & 31;
        const float4* q4 = (const float4*)Q[r];
        const float4* k4 = (const float4*)KT[i];
        float s = 0.f;
        #pragma unroll 4
        for (int kk = 0; kk < 48; kk++) {
            float4 a = q4[kk], c = k4[kk];
            s += a.x * c.x + a.y * c.y + a.z * c.z + a.w * c.w;
        }
        WQ[tid] = s * mcr[i];
    }
    __syncthreads();

    // x4 = x3 + 0.5 * t_out (in place on XS)
    if (tid < Dd) {
        float acc[RTT] = {};
        for (int i = 0; i < NT; i++) {
            float e = ET[i][tid];
            #pragma unroll
            for (int r = 0; r < RTT; r++) acc[r] += WQ[r * NT + i] * e;
        }
        #pragma unroll
        for (int r = 0; r < RTT; r++) XS[r][tid] += 0.5f * acc[r];
    }
    __syncthreads();

    // LN2 stats (8 groups of 32 lanes)
    {
        int r = tid >> 5, j = tid & 31;
        float s = 0.f, sq = 0.f;
        for (int d = j; d < Dd; d += 32) { float v = XS[r][d]; s += v; sq += v * v; }
        for (int off = 16; off > 0; off >>= 1) {
            s += __shfl_down(s, off, 32); sq += __shfl_down(sq, off, 32);
        }
        if (j == 0) {
            float mean = s / Dd;
            mv[r][0] = mean;
            mv[r][1] = rsqrtf(sq / Dd - mean * mean + EPSc);
        }
    }
    __syncthreads();

    if (tid < Dd) {
        float g = ln2_g[tid], bb = ln2_b[tid];
        float sum = 0.f;
        #pragma unroll
        for (int r = 0; r < RTT; r++)
            sum += (XS[r][tid] - mv[r][0]) * mv[r][1] * g + bb;
        atomicAdd(&pooled[b * Dd + tid], sum);
    }
}

// ---------------------------------------------------------------------------
__global__ __launch_bounds__(256) void head(
    const float* __restrict__ pooled, const float* __restrict__ Wc,
    const float* __restrict__ bc, float* __restrict__ out)
{
    int tid = threadIdx.x;
    if (tid < Bb * NCc) {
        int b = tid / NCc, c = tid - b * NCc;
        float s = 0.f;
        for (int d = 0; d < Dd; d++) s += pooled[b * Dd + d] * Wc[d * NCc + c];
        out[tid] = s * (1.0f / Tt) + bc[c];
    }
}

extern "C" void kernel_launch(void* const* d_in, const int* in_sizes, int n_in,
                              void* d_out, int out_size, void* d_ws, size_t ws_size,
                              hipStream_t stream) {
    const float* x     = (const float*)d_in[0];
    const float* W_in  = (const float*)d_in[1];
    const float* b_in  = (const float*)d_in[2];
    const float* Wv_a  = (const float*)d_in[3];
    const float* bv_a  = (const float*)d_in[4];
    const float* Wo_a  = (const float*)d_in[5];
    const float* bo_a  = (const float*)d_in[6];
    const float* ln1_g = (const float*)d_in[7];
    const float* ln1_b = (const float*)d_in[8];
    const float* pw1_w = (const float*)d_in[9];
    const float* pw1_b = (const float*)d_in[10];
    const float* dw_w  = (const float*)d_in[11];
    const float* dw_b  = (const float*)d_in[12];
    const float* bn_s  = (const float*)d_in[13];
    const float* bn_b  = (const float*)d_in[14];
    const float* pw2_w = (const float*)d_in[15];
    const float* pw2_b = (const float*)d_in[16];
    const float* Wk_t  = (const float*)d_in[17];
    const float* Wv_t  = (const float*)d_in[18];
    const float* Wq_t  = (const float*)d_in[19];
    const float* Wk_d  = (const float*)d_in[20];
    const float* Wv_d  = (const float*)d_in[21];
    const float* Wq_d  = (const float*)d_in[22];
    const float* ln2_g = (const float*)d_in[23];
    const float* ln2_b = (const float*)d_in[24];
    const float* Wc    = (const float*)d_in[25];
    const float* bc    = (const float*)d_in[26];

    float* ws = (float*)d_ws;
    size_t off = 0;
    float* x3_ws  = ws + off; off += (size_t)Bb * Tt * Dd;
    float* q_ws   = ws + off; off += (size_t)Bb * Tt * Dd;
    float* Kd_ws  = ws + off; off += Bb * ND * Dd;
    float* Ed_ws  = ws + off; off += Bb * ND * Dd;
    float* Kt_ws  = ws + off; off += Bb * NT * Dd;
    float* Et_ws  = ws + off; off += Bb * NT * Dd;
    float* pooled = ws + off; off += Bb * Dd;
    float* WinT   = ws + off; off += Dd * MEL;
    float* WqdT   = ws + off; off += Dd * Dd;
    float* WvaT   = ws + off; off += Dd * Dd;
    float* WoaT   = ws + off; off += Dd * Dd;
    float* pw1aT  = ws + off; off += Dd * Dd;
    float* pw1gT  = ws + off; off += Dd * Dd;
    float* pw2T   = ws + off; off += Dd * Dd;
    float* WqtT   = ws + off; off += Dd * Dd;
    float* WkdT   = ws + off; off += Dd * Dd;
    float* WvdT   = ws + off; off += Dd * Dd;
    float* WktT   = ws + off; off += Dd * Dd;
    float* WvtT   = ws + off; off += Dd * Dd;

    hipMemsetAsync(pooled, 0, Bb * Dd * sizeof(float), stream);

    prep<<<2048, 256, 0, stream>>>(
        W_in, Wq_d, pw1_w, pw2_w, Wq_t, Wk_d, Wv_d, Wk_t, Wv_t, Wv_a, Wo_a,
        WinT, WqdT, pw1aT, pw1gT, pw2T, WqtT, WkdT, WvdT, WktT, WvtT, WvaT, WoaT);
    delta_proj<<<Bb * ND, 256, 0, stream>>>(x, b_in, WinT, WkdT, WvdT, Kd_ws, Ed_ws);
    delta_solve<<<Bb, 256, 0, stream>>>(Kd_ws, Ed_ws);
    pipeline<<<Bb * PTILES, 256, 0, stream>>>(
        x, b_in, bv_a, bo_a, ln1_g, ln1_b, pw1_b, dw_w, dw_b, bn_s, bn_b, pw2_b,
        WinT, WqdT, WvaT, WoaT, pw1aT, pw1gT, pw2T, WqtT, WktT, WvtT,
        Kd_ws, Ed_ws, x3_ws, q_ws, Kt_ws, Et_ws);
    theta_solve<<<Bb, 256, 0, stream>>>(Kt_ws, Et_ws);
    retrieve<<<Bb * RTILES, 256, 0, stream>>>(
        x3_ws, q_ws, Kt_ws, Et_ws, ln2_g, ln2_b, pooled);
    head<<<1, 256, 0, stream>>>(pooled, Wc, bc, (float*)d_out);
}